// Round 2
// baseline (296.122 us; speedup 1.0000x reference)
//
#include <hip/hip_runtime.h>
#include <math.h>

#define Bq 128
#define Nn 8
#define LQ 32
#define LD 256
#define DD 128
#define EPSN 1e-12f
#define NEGV (-9999.0f)

// ---------------- Kernel 1: normalize q rows over D ----------------
__global__ __launch_bounds__(256) void qnorm_k(const float* __restrict__ q,
                                               float* __restrict__ qn) {
    int row  = blockIdx.x * 4 + (threadIdx.x >> 6);   // 4096 rows total
    int lane = threadIdx.x & 63;
    size_t base = (size_t)row * DD + lane * 2;
    float2 v = *reinterpret_cast<const float2*>(q + base);
    float ss = v.x * v.x + v.y * v.y;
#pragma unroll
    for (int o = 32; o; o >>= 1) ss += __shfl_xor(ss, o);
    float inv = 1.0f / fmaxf(sqrtf(ss), EPSN);
    float2 o2; o2.x = v.x * inv; o2.y = v.y * inv;
    *reinterpret_cast<float2*>(qn + base) = o2;
}

// ---------------- Kernel 2: MaxSim scores ----------------
// grid = 2 * 4 * Bq blocks; block handles (tensor, b, n-pair).
// Thread t owns d-row t of BOTH n0 and n1 (same b -> same q tile).
// q is staged in LDS and read with wave-UNIFORM ds_read_b128 (broadcast,
// zero bank conflicts, LDS pipe not VALU). Each q-read feeds 8 FMAs.
__global__ __launch_bounds__(256) void maxsim_k(const float* __restrict__ d_cq,
                                                const float* __restrict__ d_orig,
                                                const int* __restrict__ mask,
                                                const float* __restrict__ qn,
                                                float* __restrict__ scores) {
    __shared__ float q_lds[LQ][DD];   // 16 KB, natural layout; reads are uniform
    __shared__ float wm[2][4][LQ];

    int bid    = blockIdx.x;          // [0, 1024)
    int tensor = bid >> 9;
    int rem    = bid & 511;
    int b      = rem & 127;
    int npair  = rem >> 7;            // 0..3
    int n0     = npair * 2;

    int tid = threadIdx.x;

    // stage q[b] -> LDS, coalesced float4
    {
        const float4* src = reinterpret_cast<const float4*>(qn + (size_t)b * LQ * DD);
        float4* dst = reinterpret_cast<float4*>(&q_lds[0][0]);
#pragma unroll
        for (int i = 0; i < 4; ++i)
            dst[tid + 256 * i] = src[tid + 256 * i];
    }
    __syncthreads();

    const float* dten = tensor ? d_orig : d_cq;
    const float* r0 = dten + ((size_t)n0 * Bq + b) * (LD * DD) + (size_t)tid * DD;
    const float* r1 = r0 + (size_t)Bq * LD * DD;   // n0+1
    const float4* p0 = reinterpret_cast<const float4*>(r0);
    const float4* p1 = reinterpret_cast<const float4*>(r1);

    float acc0[LQ], acc1[LQ];
#pragma unroll
    for (int i = 0; i < LQ; ++i) { acc0[i] = 0.0f; acc1[i] = 0.0f; }
    float ssq0 = 0.0f, ssq1 = 0.0f;

    float4 a = p0[0], c = p1[0];
#pragma unroll 1
    for (int kq = 0; kq < 32; ++kq) {
        int nx = kq < 31 ? kq + 1 : kq;      // cmov'd address, no branch
        float4 an = p0[nx];
        float4 cn = p1[nx];
        ssq0 += a.x * a.x + a.y * a.y + a.z * a.z + a.w * a.w;
        ssq1 += c.x * c.x + c.y * c.y + c.z * c.z + c.w * c.w;
#pragma unroll
        for (int lq = 0; lq < LQ; ++lq) {
            float4 qv = *reinterpret_cast<const float4*>(&q_lds[lq][kq * 4]); // uniform
            acc0[lq] += qv.x * a.x + qv.y * a.y + qv.z * a.z + qv.w * a.w;
            acc1[lq] += qv.x * c.x + qv.y * c.y + qv.z * c.z + qv.w * c.w;
        }
        a = an; c = cn;
    }

    int mk0 = mask[((size_t)n0 * Bq + b) * LD + tid];
    int mk1 = mask[((size_t)(n0 + 1) * Bq + b) * LD + tid];
    float inv0 = 1.0f / fmaxf(sqrtf(ssq0), EPSN);
    float inv1 = 1.0f / fmaxf(sqrtf(ssq1), EPSN);

    int lane = tid & 63, wv = tid >> 6;
    float sel0 = NEGV, sel1 = NEGV;
#pragma unroll
    for (int lq = 0; lq < LQ; ++lq) {
        float s0 = mk0 ? acc0[lq] * inv0 : NEGV;
        float s1 = mk1 ? acc1[lq] * inv1 : NEGV;
#pragma unroll
        for (int o = 32; o; o >>= 1) {
            s0 = fmaxf(s0, __shfl_xor(s0, o));
            s1 = fmaxf(s1, __shfl_xor(s1, o));
        }
        if ((lane & 31) == lq) { sel0 = s0; sel1 = s1; }
    }
    if (lane < 32) { wm[0][wv][lane] = sel0; wm[1][wv][lane] = sel1; }
    __syncthreads();

    if (tid < 64) {
        int g = tid >> 5, l = tid & 31;
        float v = fmaxf(fmaxf(wm[g][0][l], wm[g][1][l]),
                        fmaxf(wm[g][2][l], wm[g][3][l]));
#pragma unroll
        for (int o = 16; o; o >>= 1) v += __shfl_xor(v, o, 32);
        if (l == 0)
            scores[tensor * (Bq * Nn) + b * Nn + (n0 + g)] = v;
    }
}

// ---------------- Kernel 3: log_softmax + KL ----------------
__global__ void loss_k(const float* __restrict__ scores, float* __restrict__ out) {
    int tid = threadIdx.x;   // 128 threads, one per b
    const float* s = scores + tid * Nn;            // student (cq)
    const float* t = scores + Bq * Nn + tid * Nn;  // teacher (orig)
    float sv[Nn], tv[Nn];
#pragma unroll
    for (int n = 0; n < Nn; ++n) { sv[n] = s[n]; tv[n] = t[n]; }
    float ms = sv[0], mt = tv[0];
#pragma unroll
    for (int n = 1; n < Nn; ++n) { ms = fmaxf(ms, sv[n]); mt = fmaxf(mt, tv[n]); }
    float es = 0.0f, et = 0.0f;
#pragma unroll
    for (int n = 0; n < Nn; ++n) { es += expf(sv[n] - ms); et += expf(tv[n] - mt); }
    float lses = ms + logf(es);
    float lset = mt + logf(et);
    double kl = 0.0;
#pragma unroll
    for (int n = 0; n < Nn; ++n) {
        float lt = tv[n] - lset;
        float ls = sv[n] - lses;
        kl += (double)expf(lt) * ((double)lt - (double)ls);
    }
#pragma unroll
    for (int o = 32; o; o >>= 1) kl += __shfl_xor(kl, o);
    __shared__ double part[2];
    if ((tid & 63) == 0) part[tid >> 6] = kl;
    __syncthreads();
    if (tid == 0) out[0] = (float)((part[0] + part[1]) / (double)Bq);
}

extern "C" void kernel_launch(void* const* d_in, const int* in_sizes, int n_in,
                              void* d_out, int out_size, void* d_ws, size_t ws_size,
                              hipStream_t stream) {
    const float* q     = (const float*)d_in[0];
    const float* dcq   = (const float*)d_in[1];
    const float* dorig = (const float*)d_in[2];
    const int*   mask  = (const int*)d_in[3];
    // labels (d_in[4]) unused by the reference loss path

    float* qn     = (float*)d_ws;                      // [B*LQ*DD] = 2MB
    float* scores = qn + (size_t)Bq * LQ * DD;         // [2][B][N] = 8KB

    qnorm_k<<<(Bq * LQ) / 4, 256, 0, stream>>>(q, qn);
    maxsim_k<<<2 * 4 * Bq, 256, 0, stream>>>(dcq, dorig, mask, qn, scores);
    loss_k<<<1, 128, 0, stream>>>(scores, (float*)d_out);
}